// Round 15
// baseline (223.045 us; speedup 1.0000x reference)
//
#include <hip/hip_runtime.h>
#include <hip/hip_bf16.h>

#define NOBJ 25
#define CONV_REP 8
#define MLP_REP 16

typedef short bf16x8 __attribute__((ext_vector_type(8)));
typedef short s16x4 __attribute__((ext_vector_type(4)));
typedef float f32x4 __attribute__((ext_vector_type(4)));
typedef unsigned int uint;

__device__ __forceinline__ short f2bf(float f) {
  __hip_bfloat16 b = __float2bfloat16(f);  // RTN
  return *reinterpret_cast<short*>(&b);
}
__device__ __forceinline__ float bf2f(short s) {
  unsigned u = ((unsigned)(unsigned short)s) << 16;
  return __uint_as_float(u);
}
__device__ __forceinline__ uint packhl(float v) {
  const short hi = f2bf(v);
  const short lo = f2bf(v - bf2f(hi));
  return ((uint)(unsigned short)hi << 16) | (uint)(unsigned short)lo;
}

// ===========================================================================
// DIAGNOSTIC ROUND 2: the exact R13 kernels (34.2us config, best so far),
// each with an internal repeat loop to clear the ~39us fill-dispatch cutoff
// and get real per-kernel counters. Repeats recompute identical values.
// ===========================================================================

// ---------------------------------------------------------------------------
// K1 (R13 verbatim + rep loop): blocks 0..127 prep, 128..639 conv.
// ---------------------------------------------------------------------------
__global__ __launch_bounds__(256, 2) void conv_prep_kernel(
    const float* __restrict__ x,    // (1024, 25*64)
    const float* __restrict__ cw0,  // (256, 64)
    const float* __restrict__ cw1,  // (256, 64)
    const float* __restrict__ cb,   // (256)
    const float* __restrict__ w1, const float* __restrict__ w2,
    const float* __restrict__ w3,
    uint* __restrict__ h0p,         // (1024, 256) packed hi|lo bf16
    short* __restrict__ wfm)        // 270336 shorts, fragment-linear hi/lo
{
  __shared__ short xs[2][32][72];        // 9216 B
  __shared__ float ab[4][2][NOBJ][68];   // 54400 B (per-wave scratch)

  if (blockIdx.x < 128) {
#pragma unroll 1
    for (int rep = 0; rep < CONV_REP; ++rep) {
      for (int j = blockIdx.x * 256 + threadIdx.x; j < 270336; j += 128 * 256) {
        const float* w; int term, f, nt;
        const bool isw3 = (j >= 262144);
        if (!isw3) {
          w = (j >> 17) ? w2 : w1;
          const int idx = j & 131071;
          term = idx >> 16; f = idx & 65535; nt = f >> 12;
        } else {
          w = w3;
          const int idx = j - 262144;  // 0..8191
          term = idx >> 12; f = idx & 4095; nt = 0;
        }
        const int ks = (f >> 9) & 7;
        const int l  = (f >> 3) & 63;
        const int jj = f & 7;
        const int col = nt * 16 + (l & 15);
        const int k   = ks * 32 + (l >> 4) * 8 + jj;
        const float v = (isw3 && col >= 10) ? 0.f : w[col * 256 + k];
        const short hi = f2bf(v);
        wfm[j] = (term == 0) ? hi : f2bf(v - bf2f(hi));
      }
    }
    return;
  }

  // ---- conv branch ----
  const int t = threadIdx.x;
  const int lane = t & 63;
  const int wv = t >> 6;
  const int r = lane & 15;
  const int g = lane >> 4;
  const int n0 = (blockIdx.x - 128) * 2;

  // one-time: W fragments (registers persist across reps)
  bf16x8 Wf[2][4][2];  // [tap][ntile][kstep]
#pragma unroll
  for (int tap = 0; tap < 2; ++tap) {
    const float* wsrc = tap ? cw1 : cw0;
#pragma unroll
    for (int ntl = 0; ntl < 4; ++ntl)
#pragma unroll
      for (int ks = 0; ks < 2; ++ks) {
        const int ch = wv * 64 + ntl * 16 + r;
        const float* p = wsrc + ch * 64 + ks * 32 + g * 8;
        const float4 a = *reinterpret_cast<const float4*>(p);
        const float4 b = *reinterpret_cast<const float4*>(p + 4);
        bf16x8 fr;
        fr[0] = f2bf(a.x); fr[1] = f2bf(a.y); fr[2] = f2bf(a.z); fr[3] = f2bf(a.w);
        fr[4] = f2bf(b.x); fr[5] = f2bf(b.y); fr[6] = f2bf(b.z); fr[7] = f2bf(b.w);
        Wf[tap][ntl][ks] = fr;
      }
  }
  float cbv[4];
#pragma unroll
  for (int ntl = 0; ntl < 4; ++ntl) cbv[ntl] = cb[wv * 64 + ntl * 16 + r];

#pragma unroll 1
  for (int rep = 0; rep < CONV_REP; ++rep) {
    __syncthreads();  // protect xs against prior rep's readers
    for (int s = 0; s < 2; ++s) {
      const float4* xg = reinterpret_cast<const float4*>(x + (size_t)(n0 + s) * (NOBJ * 64));
      for (int i = t; i < 400; i += 256) {
        float4 v = xg[i];
        s16x4 p;
        p.x = f2bf(v.x); p.y = f2bf(v.y); p.z = f2bf(v.z); p.w = f2bf(v.w);
        *reinterpret_cast<s16x4*>(&xs[s][i >> 4][(i & 15) * 4]) = p;
      }
    }
    __syncthreads();

    for (int s = 0; s < 2; ++s) {
      bf16x8 Xf[2][2];  // rows 25..31 garbage, outputs unread
#pragma unroll
      for (int mt = 0; mt < 2; ++mt)
#pragma unroll
        for (int ks = 0; ks < 2; ++ks)
          Xf[mt][ks] = *reinterpret_cast<const bf16x8*>(&xs[s][mt * 16 + r][ks * 32 + g * 8]);

      f32x4 acc[2][2][4];  // [tap][mtile][ntile]
#pragma unroll
      for (int tap = 0; tap < 2; ++tap)
#pragma unroll
        for (int mt = 0; mt < 2; ++mt)
#pragma unroll
          for (int ntl = 0; ntl < 4; ++ntl) {
            f32x4 z = {0.f, 0.f, 0.f, 0.f};
            acc[tap][mt][ntl] = z;
          }

#pragma unroll
      for (int tap = 0; tap < 2; ++tap)
#pragma unroll
        for (int mt = 0; mt < 2; ++mt)
#pragma unroll
          for (int ntl = 0; ntl < 4; ++ntl)
#pragma unroll
            for (int ks = 0; ks < 2; ++ks)
              acc[tap][mt][ntl] = __builtin_amdgcn_mfma_f32_16x16x32_bf16(
                  Xf[mt][ks], Wf[tap][ntl][ks], acc[tap][mt][ntl], 0, 0, 0);

#pragma unroll
      for (int tap = 0; tap < 2; ++tap)
#pragma unroll
        for (int mt = 0; mt < 2; ++mt)
#pragma unroll
          for (int ntl = 0; ntl < 4; ++ntl) {
            const int cl = ntl * 16 + r;
            const int row0 = mt * 16 + g * 4;
            const float badd = (tap == 0) ? cbv[ntl] : 0.f;
#pragma unroll
            for (int q = 0; q < 4; ++q)
              if (row0 + q < NOBJ) ab[wv][tap][row0 + q][cl] = acc[tap][mt][ntl][q] + badd;
          }
      // same-wave LDS RAW ordered by lgkmcnt; ab wave-private -> no barrier

      float A[NOBJ], Bv[NOBJ];
#pragma unroll
      for (int i = 0; i < NOBJ; ++i) { A[i] = ab[wv][0][i][lane]; Bv[i] = ab[wv][1][i][lane]; }
      float hacc = 0.f;
#pragma unroll
      for (int d = 1; d < NOBJ; ++d) {
        float sd = 0.f;
#pragma unroll
        for (int i = 0; i + d < NOBJ; ++i) sd += fmaxf(A[i] + Bv[i + d], 0.f);
        hacc = __builtin_fmaf(sd, 1.0f / (float)(NOBJ - d), hacc);
      }
      h0p[(size_t)(n0 + s) * 256 + t] = packhl(hacc * (1.0f / (float)(NOBJ - 1)));
    }
  }
}

// ---------------------------------------------------------------------------
// K2 (R13 verbatim + rep loop): full 3-layer MLP, 64 blocks x 512 threads.
// ---------------------------------------------------------------------------
__global__ __launch_bounds__(512, 1) void mlp_fused(
    const uint* __restrict__ inp,   // (1024,256) packed hi|lo
    const short* __restrict__ wf,   // fragment-linear hi/lo weights
    const float* __restrict__ b1, const float* __restrict__ b2,
    const float* __restrict__ b3,
    float* __restrict__ out)        // (1024, 10)
{
  __shared__ short Hs[2][2][16][272];  // [pp][term][row][k] 34816 B
  const int t = threadIdx.x, lane = t & 63, wv = t >> 6;
  const int r = lane & 15, g = lane >> 4;
  const int m0 = blockIdx.x * 16;

#pragma unroll 1
  for (int rep = 0; rep < MLP_REP; ++rep) {
    __syncthreads();  // protect Hs against prior rep's readers
    const uint4* p4 = reinterpret_cast<const uint4*>(inp) + m0 * 64;
#pragma unroll
    for (int it = 0; it < 2; ++it) {
      const int idx = t + 512 * it;  // 0..1023
      const uint4 u = p4[idx];
      const int row = idx >> 6, c = (idx & 63) * 4;
      s16x4 hi4, lo4;
      hi4.x = (short)(u.x >> 16); lo4.x = (short)(u.x & 0xffff);
      hi4.y = (short)(u.y >> 16); lo4.y = (short)(u.y & 0xffff);
      hi4.z = (short)(u.z >> 16); lo4.z = (short)(u.z & 0xffff);
      hi4.w = (short)(u.w >> 16); lo4.w = (short)(u.w & 0xffff);
      *reinterpret_cast<s16x4*>(&Hs[0][0][row][c]) = hi4;
      *reinterpret_cast<s16x4*>(&Hs[0][1][row][c]) = lo4;
    }
    __syncthreads();

    int pp = 0;
    const float* bias[2] = {b1, b2};
#pragma unroll
    for (int L = 0; L < 2; ++L) {
      const short* wl = wf + L * 131072;

      bf16x8 ahi[8], alo[8];
#pragma unroll
      for (int ks = 0; ks < 8; ++ks) {
        const int ko = ks * 32 + g * 8;
        ahi[ks] = *reinterpret_cast<const bf16x8*>(&Hs[pp][0][r][ko]);
        alo[ks] = *reinterpret_cast<const bf16x8*>(&Hs[pp][1][r][ko]);
      }

      f32x4 acc[2];
#pragma unroll
      for (int ntl = 0; ntl < 2; ++ntl) {
        const float bv = bias[L][(wv * 2 + ntl) * 16 + r];
        f32x4 a = {bv, bv, bv, bv};
        acc[ntl] = a;
      }

      {  // hi-B bulk load, then 32 MFMAs (ahi*bhi + alo*bhi)
        bf16x8 bh[2][8];
#pragma unroll
        for (int ntl = 0; ntl < 2; ++ntl)
#pragma unroll
          for (int ks = 0; ks < 8; ++ks)
            bh[ntl][ks] = *reinterpret_cast<const bf16x8*>(
                wl + (((wv * 2 + ntl) * 8 + ks) << 9) + lane * 8);
#pragma unroll
        for (int ks = 0; ks < 8; ++ks)
#pragma unroll
          for (int ntl = 0; ntl < 2; ++ntl) {
            acc[ntl] = __builtin_amdgcn_mfma_f32_16x16x32_bf16(ahi[ks], bh[ntl][ks], acc[ntl], 0, 0, 0);
            acc[ntl] = __builtin_amdgcn_mfma_f32_16x16x32_bf16(alo[ks], bh[ntl][ks], acc[ntl], 0, 0, 0);
          }
      }
      {  // lo-B bulk load, then 16 MFMAs (ahi*blo)
        bf16x8 bl[2][8];
#pragma unroll
        for (int ntl = 0; ntl < 2; ++ntl)
#pragma unroll
          for (int ks = 0; ks < 8; ++ks)
            bl[ntl][ks] = *reinterpret_cast<const bf16x8*>(
                wl + 65536 + (((wv * 2 + ntl) * 8 + ks) << 9) + lane * 8);
#pragma unroll
        for (int ks = 0; ks < 8; ++ks)
#pragma unroll
          for (int ntl = 0; ntl < 2; ++ntl)
            acc[ntl] = __builtin_amdgcn_mfma_f32_16x16x32_bf16(ahi[ks], bl[ntl][ks], acc[ntl], 0, 0, 0);
      }

      // writeback relu(acc) hi/lo into the other buffer (all 16 rows real)
#pragma unroll
      for (int ntl = 0; ntl < 2; ++ntl) {
        const int col = (wv * 2 + ntl) * 16 + r;
#pragma unroll
        for (int q = 0; q < 4; ++q) {
          const float v = fmaxf(acc[ntl][q], 0.f);
          const int row = 4 * g + q;
          const short hi = f2bf(v);
          Hs[pp ^ 1][0][row][col] = hi;
          Hs[pp ^ 1][1][row][col] = f2bf(v - bf2f(hi));
        }
      }
      __syncthreads();
      pp ^= 1;
    }

    // layer 3: one 16x16 tile (cols 10..15 zero-padded), wave 0 only
    if (wv == 0) {
      const float bv = (r < 10) ? b3[r] : 0.f;
      f32x4 acc = {bv, bv, bv, bv};
      bf16x8 ahi[8], alo[8], bh[8], bl[8];
#pragma unroll
      for (int ks = 0; ks < 8; ++ks) {
        const int ko = ks * 32 + g * 8;
        ahi[ks] = *reinterpret_cast<const bf16x8*>(&Hs[pp][0][r][ko]);
        alo[ks] = *reinterpret_cast<const bf16x8*>(&Hs[pp][1][r][ko]);
        bh[ks] = *reinterpret_cast<const bf16x8*>(wf + 262144 + (ks << 9) + lane * 8);
        bl[ks] = *reinterpret_cast<const bf16x8*>(wf + 262144 + 4096 + (ks << 9) + lane * 8);
      }
#pragma unroll
      for (int ks = 0; ks < 8; ++ks) {
        acc = __builtin_amdgcn_mfma_f32_16x16x32_bf16(ahi[ks], bh[ks], acc, 0, 0, 0);
        acc = __builtin_amdgcn_mfma_f32_16x16x32_bf16(alo[ks], bh[ks], acc, 0, 0, 0);
        acc = __builtin_amdgcn_mfma_f32_16x16x32_bf16(ahi[ks], bl[ks], acc, 0, 0, 0);
      }
      if (r < 10) {
#pragma unroll
        for (int q = 0; q < 4; ++q)
          out[(size_t)(m0 + 4 * g + q) * 10 + r] = acc[q];
      }
    }
  }
}

extern "C" void kernel_launch(void* const* d_in, const int* in_sizes, int n_in,
                              void* d_out, int out_size, void* d_ws, size_t ws_size,
                              hipStream_t stream) {
  const float* x   = (const float*)d_in[0];
  const float* cw0 = (const float*)d_in[1];
  const float* cw1 = (const float*)d_in[2];
  const float* cb  = (const float*)d_in[3];
  const float* w1  = (const float*)d_in[4];
  const float* b1  = (const float*)d_in[5];
  const float* w2  = (const float*)d_in[6];
  const float* b2  = (const float*)d_in[7];
  const float* w3  = (const float*)d_in[8];
  const float* b3  = (const float*)d_in[9];
  float* out = (float*)d_out;

  uint* h0p = (uint*)d_ws;             // 1 MB packed hi|lo
  short* wfm = (short*)(h0p + 262144); // 540 KB frag-linear weights

  conv_prep_kernel<<<640, 256, 0, stream>>>(x, cw0, cw1, cb, w1, w2, w3, h0p, wfm);
  mlp_fused<<<64, 512, 0, stream>>>(h0p, wfm, b1, b2, b3, out);
}

// Round 16
// 32.453 us; speedup vs baseline: 6.8729x; 6.8729x over previous
//
#include <hip/hip_runtime.h>
#include <hip/hip_bf16.h>

#define NOBJ 25

typedef short bf16x8 __attribute__((ext_vector_type(8)));
typedef short s16x4 __attribute__((ext_vector_type(4)));
typedef float f32x4 __attribute__((ext_vector_type(4)));
typedef unsigned int uint;

__device__ __forceinline__ short f2bf(float f) {
  __hip_bfloat16 b = __float2bfloat16(f);  // RTN
  return *reinterpret_cast<short*>(&b);
}
__device__ __forceinline__ float bf2f(short s) {
  unsigned u = ((unsigned)(unsigned short)s) << 16;
  return __uint_as_float(u);
}
__device__ __forceinline__ uint packhl(float v) {
  const short hi = f2bf(v);
  const short lo = f2bf(v - bf2f(hi));
  return ((uint)(unsigned short)hi << 16) | (uint)(unsigned short)lo;
}

// ---------------------------------------------------------------------------
// K1 (R13 verbatim): blocks 0..127 MLP-weight prep; 128..639 conv (2 samples,
// wave-local pairwise), h written packed hi|lo.
// ---------------------------------------------------------------------------
__global__ __launch_bounds__(256, 2) void conv_prep_kernel(
    const float* __restrict__ x,    // (1024, 25*64)
    const float* __restrict__ cw0,  // (256, 64)
    const float* __restrict__ cw1,  // (256, 64)
    const float* __restrict__ cb,   // (256)
    const float* __restrict__ w1, const float* __restrict__ w2,
    const float* __restrict__ w3,
    uint* __restrict__ h0p,         // (1024, 256) packed hi|lo bf16
    short* __restrict__ wfm)        // 270336 shorts, fragment-linear hi/lo
{
  __shared__ short xs[2][32][72];        // 9216 B
  __shared__ float ab[4][2][NOBJ][68];   // 54400 B (per-wave scratch)

  if (blockIdx.x < 128) {
    for (int j = blockIdx.x * 256 + threadIdx.x; j < 270336; j += 128 * 256) {
      const float* w; int term, f, nt;
      const bool isw3 = (j >= 262144);
      if (!isw3) {
        w = (j >> 17) ? w2 : w1;
        const int idx = j & 131071;
        term = idx >> 16; f = idx & 65535; nt = f >> 12;
      } else {
        w = w3;
        const int idx = j - 262144;  // 0..8191
        term = idx >> 12; f = idx & 4095; nt = 0;
      }
      const int ks = (f >> 9) & 7;
      const int l  = (f >> 3) & 63;
      const int jj = f & 7;
      const int col = nt * 16 + (l & 15);
      const int k   = ks * 32 + (l >> 4) * 8 + jj;
      const float v = (isw3 && col >= 10) ? 0.f : w[col * 256 + k];
      const short hi = f2bf(v);
      wfm[j] = (term == 0) ? hi : f2bf(v - bf2f(hi));
    }
    return;
  }

  // ---- conv branch ----
  const int t = threadIdx.x;
  const int lane = t & 63;
  const int wv = t >> 6;
  const int r = lane & 15;
  const int g = lane >> 4;
  const int n0 = (blockIdx.x - 128) * 2;

  // x staging first (cold misses issued early)
  for (int s = 0; s < 2; ++s) {
    const float4* xg = reinterpret_cast<const float4*>(x + (size_t)(n0 + s) * (NOBJ * 64));
    for (int i = t; i < 400; i += 256) {
      float4 v = xg[i];
      s16x4 p;
      p.x = f2bf(v.x); p.y = f2bf(v.y); p.z = f2bf(v.z); p.w = f2bf(v.w);
      *reinterpret_cast<s16x4*>(&xs[s][i >> 4][(i & 15) * 4]) = p;
    }
  }

  bf16x8 Wf[2][4][2];  // [tap][ntile][kstep]
#pragma unroll
  for (int tap = 0; tap < 2; ++tap) {
    const float* wsrc = tap ? cw1 : cw0;
#pragma unroll
    for (int ntl = 0; ntl < 4; ++ntl)
#pragma unroll
      for (int ks = 0; ks < 2; ++ks) {
        const int ch = wv * 64 + ntl * 16 + r;
        const float* p = wsrc + ch * 64 + ks * 32 + g * 8;
        const float4 a = *reinterpret_cast<const float4*>(p);
        const float4 b = *reinterpret_cast<const float4*>(p + 4);
        bf16x8 fr;
        fr[0] = f2bf(a.x); fr[1] = f2bf(a.y); fr[2] = f2bf(a.z); fr[3] = f2bf(a.w);
        fr[4] = f2bf(b.x); fr[5] = f2bf(b.y); fr[6] = f2bf(b.z); fr[7] = f2bf(b.w);
        Wf[tap][ntl][ks] = fr;
      }
  }
  float cbv[4];
#pragma unroll
  for (int ntl = 0; ntl < 4; ++ntl) cbv[ntl] = cb[wv * 64 + ntl * 16 + r];

  __syncthreads();

  for (int s = 0; s < 2; ++s) {
    bf16x8 Xf[2][2];  // rows 25..31 garbage, outputs unread
#pragma unroll
    for (int mt = 0; mt < 2; ++mt)
#pragma unroll
      for (int ks = 0; ks < 2; ++ks)
        Xf[mt][ks] = *reinterpret_cast<const bf16x8*>(&xs[s][mt * 16 + r][ks * 32 + g * 8]);

    f32x4 acc[2][2][4];  // [tap][mtile][ntile]
#pragma unroll
    for (int tap = 0; tap < 2; ++tap)
#pragma unroll
      for (int mt = 0; mt < 2; ++mt)
#pragma unroll
        for (int ntl = 0; ntl < 4; ++ntl) {
          f32x4 z = {0.f, 0.f, 0.f, 0.f};
          acc[tap][mt][ntl] = z;
        }

#pragma unroll
    for (int tap = 0; tap < 2; ++tap)
#pragma unroll
      for (int mt = 0; mt < 2; ++mt)
#pragma unroll
        for (int ntl = 0; ntl < 4; ++ntl)
#pragma unroll
          for (int ks = 0; ks < 2; ++ks)
            acc[tap][mt][ntl] = __builtin_amdgcn_mfma_f32_16x16x32_bf16(
                Xf[mt][ks], Wf[tap][ntl][ks], acc[tap][mt][ntl], 0, 0, 0);

#pragma unroll
    for (int tap = 0; tap < 2; ++tap)
#pragma unroll
      for (int mt = 0; mt < 2; ++mt)
#pragma unroll
        for (int ntl = 0; ntl < 4; ++ntl) {
          const int cl = ntl * 16 + r;
          const int row0 = mt * 16 + g * 4;
          const float badd = (tap == 0) ? cbv[ntl] : 0.f;
#pragma unroll
          for (int q = 0; q < 4; ++q)
            if (row0 + q < NOBJ) ab[wv][tap][row0 + q][cl] = acc[tap][mt][ntl][q] + badd;
        }
    // same-wave LDS RAW ordered by lgkmcnt; ab wave-private -> no barrier

    float A[NOBJ], Bv[NOBJ];
#pragma unroll
    for (int i = 0; i < NOBJ; ++i) { A[i] = ab[wv][0][i][lane]; Bv[i] = ab[wv][1][i][lane]; }
    float hacc = 0.f;
#pragma unroll
    for (int d = 1; d < NOBJ; ++d) {
      float sd = 0.f;
#pragma unroll
      for (int i = 0; i + d < NOBJ; ++i) sd += fmaxf(A[i] + Bv[i + d], 0.f);
      hacc = __builtin_fmaf(sd, 1.0f / (float)(NOBJ - d), hacc);
    }
    h0p[(size_t)(n0 + s) * 256 + t] = packhl(hacc * (1.0f / (float)(NOBJ - 1)));
  }
}

// ---------------------------------------------------------------------------
// K2 v2: full 3-layer MLP. 64 blocks x 1024 threads (16 waves = 4 waves/SIMD,
// 2x the latency hiding of R13's 8-wave version on the same 34MB L2 stream).
// Wave wv owns one 16-col tile (nt = wv), all 16 M-rows real. Register plan
// for the 128-VGPR cap: bh[8]+bl[8] bulk (64) + resident ahi[8] (32) +
// per-ks streamed alo (8) + acc (4) ~= 115. Hs ping-pong as in R13.
// ---------------------------------------------------------------------------
__global__ __launch_bounds__(1024, 4) void mlp_fused(
    const uint* __restrict__ inp,   // (1024,256) packed hi|lo
    const short* __restrict__ wf,   // fragment-linear hi/lo weights
    const float* __restrict__ b1, const float* __restrict__ b2,
    const float* __restrict__ b3,
    float* __restrict__ out)        // (1024, 10)
{
  __shared__ short Hs[2][2][16][272];  // [pp][term][row][k] 34816 B
  const int t = threadIdx.x, lane = t & 63, wv = t >> 6;
  const int r = lane & 15, g = lane >> 4;
  const int m0 = blockIdx.x * 16;

  // stage 16 rows packed -> hi/lo LDS (1024 uint4s, one per thread)
  {
    const uint4 u = (reinterpret_cast<const uint4*>(inp) + m0 * 64)[t];
    const int row = t >> 6, c = (t & 63) * 4;
    s16x4 hi4, lo4;
    hi4.x = (short)(u.x >> 16); lo4.x = (short)(u.x & 0xffff);
    hi4.y = (short)(u.y >> 16); lo4.y = (short)(u.y & 0xffff);
    hi4.z = (short)(u.z >> 16); lo4.z = (short)(u.z & 0xffff);
    hi4.w = (short)(u.w >> 16); lo4.w = (short)(u.w & 0xffff);
    *reinterpret_cast<s16x4*>(&Hs[0][0][row][c]) = hi4;
    *reinterpret_cast<s16x4*>(&Hs[0][1][row][c]) = lo4;
  }
  __syncthreads();

  int pp = 0;
  const float* bias[2] = {b1, b2};
#pragma unroll
  for (int L = 0; L < 2; ++L) {
    const short* wl = wf + L * 131072;

    // bulk-load this wave's B fragments (hi + lo), 16 x b128
    bf16x8 bh[8], bl[8];
#pragma unroll
    for (int ks = 0; ks < 8; ++ks) {
      bh[ks] = *reinterpret_cast<const bf16x8*>(wl + ((wv * 8 + ks) << 9) + lane * 8);
      bl[ks] = *reinterpret_cast<const bf16x8*>(wl + 65536 + ((wv * 8 + ks) << 9) + lane * 8);
    }
    // resident A-hi fragments (8 x ds_read_b128)
    bf16x8 ahi[8];
#pragma unroll
    for (int ks = 0; ks < 8; ++ks)
      ahi[ks] = *reinterpret_cast<const bf16x8*>(&Hs[pp][0][r][ks * 32 + g * 8]);

    const float bv = bias[L][wv * 16 + r];
    f32x4 acc = {bv, bv, bv, bv};
#pragma unroll
    for (int ks = 0; ks < 8; ++ks) {
      const bf16x8 alo = *reinterpret_cast<const bf16x8*>(&Hs[pp][1][r][ks * 32 + g * 8]);
      acc = __builtin_amdgcn_mfma_f32_16x16x32_bf16(ahi[ks], bh[ks], acc, 0, 0, 0);
      acc = __builtin_amdgcn_mfma_f32_16x16x32_bf16(alo, bh[ks], acc, 0, 0, 0);
      acc = __builtin_amdgcn_mfma_f32_16x16x32_bf16(ahi[ks], bl[ks], acc, 0, 0, 0);
    }

    // writeback relu(acc) hi/lo into the other buffer: wave wv -> cols
    // [16wv, 16wv+16), rows 4g+q (all 16 rows real; full tile covered once)
    const int col = wv * 16 + r;
#pragma unroll
    for (int q = 0; q < 4; ++q) {
      const float v = fmaxf(acc[q], 0.f);
      const int row = 4 * g + q;
      const short hi = f2bf(v);
      Hs[pp ^ 1][0][row][col] = hi;
      Hs[pp ^ 1][1][row][col] = f2bf(v - bf2f(hi));
    }
    __syncthreads();
    pp ^= 1;
  }

  // layer 3: one 16x16 tile (cols 10..15 zero-padded), wave 0 only
  if (wv == 0) {
    const float bv = (r < 10) ? b3[r] : 0.f;
    f32x4 acc = {bv, bv, bv, bv};
    bf16x8 ahi[8], alo[8], bh[8], bl[8];
#pragma unroll
    for (int ks = 0; ks < 8; ++ks) {
      const int ko = ks * 32 + g * 8;
      ahi[ks] = *reinterpret_cast<const bf16x8*>(&Hs[pp][0][r][ko]);
      alo[ks] = *reinterpret_cast<const bf16x8*>(&Hs[pp][1][r][ko]);
      bh[ks] = *reinterpret_cast<const bf16x8*>(wf + 262144 + (ks << 9) + lane * 8);
      bl[ks] = *reinterpret_cast<const bf16x8*>(wf + 262144 + 4096 + (ks << 9) + lane * 8);
    }
#pragma unroll
    for (int ks = 0; ks < 8; ++ks) {
      acc = __builtin_amdgcn_mfma_f32_16x16x32_bf16(ahi[ks], bh[ks], acc, 0, 0, 0);
      acc = __builtin_amdgcn_mfma_f32_16x16x32_bf16(alo[ks], bh[ks], acc, 0, 0, 0);
      acc = __builtin_amdgcn_mfma_f32_16x16x32_bf16(ahi[ks], bl[ks], acc, 0, 0, 0);
    }
    if (r < 10) {
#pragma unroll
      for (int q = 0; q < 4; ++q)
        out[(size_t)(m0 + 4 * g + q) * 10 + r] = acc[q];
    }
  }
}

extern "C" void kernel_launch(void* const* d_in, const int* in_sizes, int n_in,
                              void* d_out, int out_size, void* d_ws, size_t ws_size,
                              hipStream_t stream) {
  const float* x   = (const float*)d_in[0];
  const float* cw0 = (const float*)d_in[1];
  const float* cw1 = (const float*)d_in[2];
  const float* cb  = (const float*)d_in[3];
  const float* w1  = (const float*)d_in[4];
  const float* b1  = (const float*)d_in[5];
  const float* w2  = (const float*)d_in[6];
  const float* b2  = (const float*)d_in[7];
  const float* w3  = (const float*)d_in[8];
  const float* b3  = (const float*)d_in[9];
  float* out = (float*)d_out;

  uint* h0p = (uint*)d_ws;             // 1 MB packed hi|lo
  short* wfm = (short*)(h0p + 262144); // 540 KB frag-linear weights

  conv_prep_kernel<<<640, 256, 0, stream>>>(x, cw0, cw1, cb, w1, w2, w3, h0p, wfm);
  mlp_fused<<<64, 1024, 0, stream>>>(h0p, wfm, b1, b2, b3, out);
}